// Round 5
// baseline (337.401 us; speedup 1.0000x reference)
//
#include <hip/hip_runtime.h>

#define Bsz 2
#define Sq  4096
#define Dm  1024
#define NH  16
#define HD  64

typedef __attribute__((ext_vector_type(8))) short short8;   // 8 bf16 = 4 VGPRs
typedef __attribute__((ext_vector_type(4))) float f32x4;
typedef __attribute__((ext_vector_type(2))) __fp16 fp16x2;  // cvt_pkrtz result type
typedef __attribute__((ext_vector_type(4))) _Float16 half4v;
typedef __attribute__((ext_vector_type(8))) _Float16 half8v; // K=32 f16 MFMA operand

__device__ __forceinline__ unsigned short f2bf(float x) {
    unsigned int u = __float_as_uint(x);
    u += 0x7fffu + ((u >> 16) & 1u);            // round-to-nearest-even
    return (unsigned short)(u >> 16);
}

__device__ __forceinline__ void gl2lds16(const unsigned short* g, unsigned short* l) {
    __builtin_amdgcn_global_load_lds(
        (const __attribute__((address_space(1))) unsigned int*)g,
        (__attribute__((address_space(3))) unsigned int*)l, 16, 0, 0);
}

// ---------------------------------------------------------------------------
// fp32 -> bf16 bulk convert (X). 4 elems/thread.
// ---------------------------------------------------------------------------
__global__ __launch_bounds__(256) void cvt_bf16(const float4* __restrict__ in,
                                                ushort4* __restrict__ out) {
    const int i = blockIdx.x * 256 + threadIdx.x;
    const float4 v = in[i];
    ushort4 r;
    r.x = f2bf(v.x); r.y = f2bf(v.y); r.z = f2bf(v.z); r.w = f2bf(v.w);
    out[i] = r;
}

// ---------------------------------------------------------------------------
// Fused weight transpose: W[K][N] fp32 -> WtAll[z][N][K] bf16, z in {q,k,v,o}
// ---------------------------------------------------------------------------
__global__ __launch_bounds__(256) void wtrans4(const float* __restrict__ Wq,
                                               const float* __restrict__ Wk,
                                               const float* __restrict__ Wv,
                                               const float* __restrict__ Wo,
                                               unsigned short* __restrict__ WtAll) {
    __shared__ float tile[64][65];
    const int z = blockIdx.z;
    const float* W = (z == 0) ? Wq : (z == 1) ? Wk : (z == 2) ? Wv : Wo;
    unsigned short* Wt = WtAll + (size_t)z * Dm * Dm;
    const int k0 = blockIdx.y * 64, n0 = blockIdx.x * 64;
    const int t = threadIdx.x;
    #pragma unroll
    for (int i = 0; i < 16; ++i) {
        const int idx = t + i * 256, r = idx >> 6, c = idx & 63;
        tile[r][c] = W[(size_t)(k0 + r) * Dm + n0 + c];
    }
    __syncthreads();
    #pragma unroll
    for (int i = 0; i < 16; ++i) {
        const int idx = t + i * 256, rr = idx >> 6, cc = idx & 63;
        Wt[(size_t)(n0 + rr) * Dm + k0 + cc] = f2bf(tile[cc][rr]);
    }
}

// ===========================================================================
// Shared GEMM core: 128x128 tile, BK=32, bf16 MFMA, global_load_lds staging.
// ===========================================================================
struct GemmCtx {
    int wm, wn, quad, c16;
    f32x4 acc[4][4];
};

__device__ __forceinline__ void gemm_core(
    const unsigned short* __restrict__ A,
    const unsigned short* __restrict__ Bt,
    int bm, int bn, unsigned short* As, unsigned short* Bs, GemmCtx& cx)
{
    const int t    = threadIdx.x;
    const int w    = t >> 6;
    const int lane = t & 63;
    cx.quad = lane >> 4;
    cx.c16  = lane & 15;
    cx.wm = (w >> 1) * 64;
    cx.wn = (w & 1) * 64;

    #pragma unroll
    for (int i = 0; i < 4; ++i)
        #pragma unroll
        for (int j = 0; j < 4; ++j)
            cx.acc[i][j] = (f32x4){0.f, 0.f, 0.f, 0.f};

    const int srow = lane >> 2, soff = (lane & 3) * 8;
    const unsigned short* Ag0 = A  + (size_t)(bm + w * 16 + srow) * Dm + soff;
    const unsigned short* Ag1 = Ag0 + (size_t)64 * Dm;
    const unsigned short* Bg0 = Bt + (size_t)(bn + w * 16 + srow) * Dm + soff;
    const unsigned short* Bg1 = Bg0 + (size_t)64 * Dm;
    unsigned short* Al0 = As + (w * 16) * 32;
    unsigned short* Al1 = As + (64 + w * 16) * 32;
    unsigned short* Bl0 = Bs + (w * 16) * 32;
    unsigned short* Bl1 = Bs + (64 + w * 16) * 32;

    for (int k0 = 0; k0 < Dm; k0 += 32) {
        __syncthreads();
        gl2lds16(Ag0 + k0, Al0);
        gl2lds16(Ag1 + k0, Al1);
        gl2lds16(Bg0 + k0, Bl0);
        gl2lds16(Bg1 + k0, Bl1);
        __syncthreads();

        short8 af[4], bf[4];
        #pragma unroll
        for (int mt = 0; mt < 4; ++mt)
            af[mt] = *(const short8*)(As + (cx.wm + mt * 16 + cx.c16) * 32 + cx.quad * 8);
        #pragma unroll
        for (int nt = 0; nt < 4; ++nt)
            bf[nt] = *(const short8*)(Bs + (cx.wn + nt * 16 + cx.c16) * 32 + cx.quad * 8);
        #pragma unroll
        for (int mt = 0; mt < 4; ++mt)
            #pragma unroll
            for (int nt = 0; nt < 4; ++nt)
                cx.acc[mt][nt] = __builtin_amdgcn_mfma_f32_16x16x32_bf16(
                    af[mt], bf[nt], cx.acc[mt][nt], 0, 0, 0);
    }
}

// ---------------------------------------------------------------------------
// Fused QKV projection: A=Xb[8192,1024], Bt=WtAll (Wq|Wk|Wv rows, 3072x1024).
// V output is transposed in-LDS so Vt writes are fully coalesced (the old
// path scattered 2.1M 8B stores at stride Sq*2B).
// ---------------------------------------------------------------------------
__global__ __launch_bounds__(256) void gemm_qkv(
    const unsigned short* __restrict__ A,
    const unsigned short* __restrict__ WtAll,
    const float* __restrict__ bq, const float* __restrict__ bk,
    const float* __restrict__ bv,
    unsigned short* __restrict__ Qh, unsigned short* __restrict__ Kh,
    unsigned short* __restrict__ Vt, float qscale)
{
    __shared__ unsigned short Smem[128 * 144];     // core: As|Bs (8K hw); epi: V-tile
    unsigned short* As = Smem;
    unsigned short* Bs = Smem + 128 * 32;
    const int bm = blockIdx.y * 128;
    const int bn = blockIdx.x * 128;          // 0..3072
    GemmCtx cx;
    gemm_core(A, WtAll, bm, bn, As, Bs, cx);

    const int which = bn >> 10;               // 0=Q 1=K 2=V
    const float* bias = (which == 0) ? bq : (which == 1) ? bk : bv;
    const float osc = (which == 0) ? qscale : 1.0f;

    if (which < 2) {
        #pragma unroll
        for (int mt = 0; mt < 4; ++mt) {
            const int m0 = bm + cx.wm + mt * 16 + cx.quad * 4;
            #pragma unroll
            for (int nt = 0; nt < 4; ++nt) {
                const int n  = bn + cx.wn + nt * 16 + cx.c16;
                const int nl = n & 1023;
                const float bvv = bias[nl];
                const int h = (nl >> 6), d = nl & 63;
                unsigned short* C = (which == 0) ? Qh : Kh;
                #pragma unroll
                for (int r = 0; r < 4; ++r) {
                    const int m = m0 + r;
                    const int b = m >> 12, s = m & (Sq - 1);
                    C[((size_t)(b * NH + h) * Sq + s) * HD + d] =
                        f2bf((cx.acc[mt][nt][r] + bvv) * osc);
                }
            }
        }
    } else {
        // ---- V: transpose in LDS, then coalesced write to Vt[bh][d][Sq] ----
        __syncthreads();                       // done with As/Bs
        #pragma unroll
        for (int mt = 0; mt < 4; ++mt) {
            const int mloc = cx.wm + mt * 16 + cx.quad * 4;
            #pragma unroll
            for (int nt = 0; nt < 4; ++nt) {
                const int nloc = cx.wn + nt * 16 + cx.c16;
                const float bvv = bias[(bn & 1023) + nloc];
                union { fp16x2 h2[2]; unsigned int u[2]; } pk;
                pk.h2[0] = __builtin_amdgcn_cvt_pkrtz(cx.acc[mt][nt][0] + bvv,
                                                      cx.acc[mt][nt][1] + bvv);
                pk.h2[1] = __builtin_amdgcn_cvt_pkrtz(cx.acc[mt][nt][2] + bvv,
                                                      cx.acc[mt][nt][3] + bvv);
                *(uint2*)(Smem + nloc * 144 + mloc) = make_uint2(pk.u[0], pk.u[1]);
            }
        }
        __syncthreads();
        const int t = threadIdx.x;
        const int r2 = t >> 1, seg = t & 1;    // r2: n-local row, seg: 64-col half
        const int h = ((bn - 2048) >> 6) + (r2 >> 6);
        const int d = r2 & 63;
        const int bb = bm >> 12;
        unsigned short* dst = Vt + ((size_t)(bb * NH + h) * HD + d) * Sq
                                 + (bm & (Sq - 1)) + seg * 64;
        const unsigned short* src = Smem + r2 * 144 + seg * 64;
        #pragma unroll
        for (int j2 = 0; j2 < 8; ++j2)         // 8 x int4 (8 hw each) = 64 hw
            *(int4*)(dst + j2 * 8) = *(const int4*)(src + j2 * 8);
    }
}

// ---------------------------------------------------------------------------
// Output projection: fp32 out = AO @ Wo^T + bo
// ---------------------------------------------------------------------------
__global__ __launch_bounds__(256) void gemm_o(
    const unsigned short* __restrict__ A,
    const unsigned short* __restrict__ Bt,
    const float* __restrict__ bias, float* __restrict__ C)
{
    __shared__ unsigned short As[128 * 32];
    __shared__ unsigned short Bs[128 * 32];
    const int bm = blockIdx.y * 128;
    const int bn = blockIdx.x * 128;
    GemmCtx cx;
    gemm_core(A, Bt, bm, bn, As, Bs, cx);

    #pragma unroll
    for (int mt = 0; mt < 4; ++mt) {
        const int m0 = bm + cx.wm + mt * 16 + cx.quad * 4;
        #pragma unroll
        for (int nt = 0; nt < 4; ++nt) {
            const int n = bn + cx.wn + nt * 16 + cx.c16;
            const float bvv = bias[n];
            #pragma unroll
            for (int r = 0; r < 4; ++r)
                C[(size_t)(m0 + r) * Dm + n] = cx.acc[mt][nt][r] + bvv;
        }
    }
}

// ---------------------------------------------------------------------------
// Flash attention v9: instruction-granular MFMA/VALU interleave.
//   v6/v7/v8 all show MfmaUtil+VALUBusy ~= 100%: cluster-level rotation can't
//   co-issue because in-order issue blocks at back-to-back MFMAs (pipe busy
//   ~19cy each) with the VALU stuck behind the cluster. v9: slot = 1 MFMA,
//   sched_barrier(0), ~6 VALU of the PREVIOUS chunk's softmax; dependent QK
//   MFMA pairs at distance 4. K staged via global_load_lds with pre-swizzled
//   per-lane SOURCE (m173): LDS[r][c] = G[r][c^(r&7)], read at c = quad^(r&7).
//   V stays reg-staged (key-permutation), writes woven into PV Lsum slots.
// Q,K: bf16 [B*NH][Sq][64] (Q pre-scaled by 0.125*log2e). Vt: fp16 [B*NH][64][Sq].
// ---------------------------------------------------------------------------
__global__ __launch_bounds__(256, 2) void attn_mfma9(
    const unsigned short* __restrict__ Q,
    const unsigned short* __restrict__ K,
    const unsigned short* __restrict__ Vt,
    unsigned short* __restrict__ AO)
{
    __shared__ unsigned short Ks[2][64 * 64];   // [key][d] bf16, XOR-swizzled rows
    __shared__ unsigned short Vs[2][64 * 64];   // [d][pos] fp16, key-permuted + swz

    // XCD-grouped decode: xcd = wg&7, 64 blocks per XCD cover 4 bh x 16 qt.
    const int wg  = blockIdx.x;               // 0..511
    const int j   = wg >> 3;                  // 0..63 within XCD
    const int bh  = (wg & 7) * 4 + (j >> 4);  // 0..31
    const int qt  = j & 15;                   // 0..15 (256 queries each)
    const int b = bh >> 4, h = bh & 15;
    const int t    = threadIdx.x;
    const int w    = t >> 6;
    const int lane = t & 63;
    const int quad = lane >> 4;
    const int c16  = lane & 15;
    const size_t base = (size_t)bh * Sq * HD;

    // Q B-frags: 4 query-groups x 2 k-halves, held all kernel
    short8 qf[4][2];
    #pragma unroll
    for (int qg = 0; qg < 4; ++qg) {
        const unsigned short* qp =
            Q + base + (size_t)(qt * 256 + w * 64 + qg * 16 + c16) * HD;
        qf[qg][0] = *(const short8*)(qp + quad * 8);
        qf[qg][1] = *(const short8*)(qp + 32 + quad * 8);
    }

    f32x4 O[4][4];                 // [qg][d-group]
    f32x4 Lsum[4];
    #pragma unroll
    for (int qg = 0; qg < 4; ++qg) {
        Lsum[qg] = (f32x4){0.f, 0.f, 0.f, 0.f};
        #pragma unroll
        for (int g = 0; g < 4; ++g)
            O[qg][g] = (f32x4){0.f, 0.f, 0.f, 0.f};
    }
    half8v ones8;
    #pragma unroll
    for (int i = 0; i < 8; ++i) ones8[i] = (_Float16)1.f;
    const f32x4 zero4 = (f32x4){0.f, 0.f, 0.f, 0.f};

    // ---- K staging geometry: global_load_lds, pre-swizzled source ----
    // wave w stages key rows 16w..16w+15 (2 instrs x 8 rows); lane l writes
    // LDS row 16w+8i+(l>>3), chunk (l&7); source chunk (l&7)^(l>>3).
    const int lrow = lane >> 3, lchunk = lane & 7;
    const unsigned short* kgA = K + base + (size_t)(16 * w + lrow) * HD
                                  + (lchunk ^ lrow) * 8;
    const unsigned short* kgB = kgA + (size_t)8 * HD;
    unsigned short* klA = &Ks[0][0] + (16 * w) * 64;
    unsigned short* klB = klA + 8 * 64;

    // ---- V staging geometry (reg path, key-permuted + swizzled) ----
    const int srow = t >> 2, sc4 = (t & 3) * 8;
    const int swr = (srow & 7) << 3;
    const int f0 = (sc4 < 16) ? sc4 * 2 : (sc4 - 16) * 2 + 4;        // {0,16,4,20}
    const int f1 = (sc4 + 4 < 16) ? (sc4 + 4) * 2 : (sc4 - 12) * 2 + 4; // {8,24,12,28}
    const int vc0 = f0 ^ swr, vc1 = f1 ^ swr;
    const int vc2 = (32 + f0) ^ swr, vc3 = (32 + f1) ^ swr;

    const unsigned short* vg = Vt + base + (size_t)srow * Sq + sc4;
    unsigned short* vsl = &Vs[0][0] + srow * 64;
    const int LBUF = 64 * 64;

    // ---- prologue: stage tile 0 into buf 0 ----
    gl2lds16(kgA, klA);
    gl2lds16(kgB, klB);
    int4 vr0 = *(const int4*)(vg);
    int4 vr1 = *(const int4*)(vg + 32);
    *(uint2*)(vsl + vc0) = make_uint2(vr0.x, vr0.y);
    *(uint2*)(vsl + vc1) = make_uint2(vr0.z, vr0.w);
    *(uint2*)(vsl + vc2) = make_uint2(vr1.x, vr1.y);
    *(uint2*)(vsl + vc3) = make_uint2(vr1.z, vr1.w);

    for (int kt = 0; kt < Sq / 64; ++kt) {
        const int cur = kt & 1;
        __syncthreads();                      // buf cur staged; buf cur^1 free
        const int nb = cur ^ 1;
        const bool pre = (kt + 1 < Sq / 64);
        if (pre) {                            // async: next K tile direct to LDS
            const unsigned short* kp = kgA + (size_t)(kt + 1) * 64 * HD;
            gl2lds16(kp, klA + nb * LBUF);
            gl2lds16(kp + (size_t)8 * HD, klB + nb * LBUF);
            const unsigned short* vp = vg + (kt + 1) * 64;
            vr0 = *(const int4*)(vp);
            vr1 = *(const int4*)(vp + 32);
        }
        unsigned short* vdst = vsl + nb * LBUF;

        const unsigned short* ksb = &Ks[cur][0];
        const unsigned short* vsb = &Vs[cur][0];

        auto krd = [&](int nt5, short8& r0, short8& r1) {
            const int krow = nt5 * 16 + c16;
            const int ksw = (krow & 7) << 3;
            r0 = *(const short8*)(ksb + krow * 64 + ((quad * 8) ^ ksw));
            r1 = *(const short8*)(ksb + krow * 64 + ((32 + quad * 8) ^ ksw));
        };
        auto exppack = [&](const f32x4 zv) -> half4v {
            const float p0 = __builtin_amdgcn_exp2f(zv[0]);
            const float p1 = __builtin_amdgcn_exp2f(zv[1]);
            const float p2 = __builtin_amdgcn_exp2f(zv[2]);
            const float p3 = __builtin_amdgcn_exp2f(zv[3]);
            union { fp16x2 h2[2]; half4v h4; } pk;
            pk.h2[0] = __builtin_amdgcn_cvt_pkrtz(p0, p1);
            pk.h2[1] = __builtin_amdgcn_cvt_pkrtz(p2, p3);
            return pk.h4;
        };

        short8 kA0, kA1, kB0, kB1;
        f32x4 zA[4], zB[4];
        half8v P32a[4], P32b[4];
        half8v vfr[4];

        // interleaved nt-step: MFMA(this chunk) || softmax(previous chunk)
        auto ntstep = [&](const short8 kc0, const short8 kc1, f32x4* zw,
                          const f32x4* zr, half8v* Pdst, const int hi) {
            #pragma unroll
            for (int q = 0; q < 4; ++q) {
                zw[q] = __builtin_amdgcn_mfma_f32_16x16x32_bf16(
                    kc0, qf[q][0], zero4, 0, 0, 0);
                __builtin_amdgcn_sched_barrier(0);
                ((half4v*)&Pdst[q])[hi] = exppack(zr[q]);
                __builtin_amdgcn_sched_barrier(0);
            }
            #pragma unroll
            for (int q = 0; q < 4; ++q) {
                zw[q] = __builtin_amdgcn_mfma_f32_16x16x32_bf16(
                    kc1, qf[q][1], zw[q], 0, 0, 0);
                __builtin_amdgcn_sched_barrier(0);
            }
        };

        krd(0, kA0, kA1);
        krd(1, kB0, kB1);

        // NT0: plain MFMA (no prior softmax work exists yet this tile)
        #pragma unroll
        for (int q = 0; q < 4; ++q)
            zA[q] = __builtin_amdgcn_mfma_f32_16x16x32_bf16(
                kA0, qf[q][0], zero4, 0, 0, 0);
        #pragma unroll
        for (int q = 0; q < 4; ++q)
            zA[q] = __builtin_amdgcn_mfma_f32_16x16x32_bf16(
                kA1, qf[q][1], zA[q], 0, 0, 0);
        __builtin_amdgcn_sched_barrier(0);

        krd(2, kA0, kA1);                     // kA free -> nt2 frags
        ntstep(kB0, kB1, zB, zA, P32a, 0);    // NT1 || exp(nt0) -> P32a.lo
        krd(3, kB0, kB1);                     // kB free -> nt3 frags
        ntstep(kA0, kA1, zA, zB, P32a, 1);    // NT2 || exp(nt1) -> P32a.hi
        #pragma unroll
        for (int g = 0; g < 4; ++g) {         // V frags for PV cc0
            const int vrow = g * 16 + c16;
            vfr[g] = *(const half8v*)
                (vsb + vrow * 64 + ((quad * 8) ^ ((vrow & 7) << 3)));
        }
        ntstep(kB0, kB1, zB, zA, P32b, 0);    // NT3 || exp(nt2) -> P32b.lo

        // PV cc0: O += P(0:31) @ V || exp(nt3) -> P32b.hi ; prefetch cc1 V frags
        #pragma unroll
        for (int g = 0; g < 4; ++g) {
            #pragma unroll
            for (int q = 0; q < 4; ++q)
                O[q][g] = __builtin_amdgcn_mfma_f32_16x16x32_f16(
                    P32a[q], vfr[g], O[q][g], 0, 0, 0);
            __builtin_amdgcn_sched_barrier(0);
            ((half4v*)&P32b[g])[1] = exppack(zB[g]);
            __builtin_amdgcn_sched_barrier(0);
            const int vrow = g * 16 + c16;
            vfr[g] = *(const half8v*)
                (vsb + vrow * 64 + ((32 + quad * 8) ^ ((vrow & 7) << 3)));
            __builtin_amdgcn_sched_barrier(0);
        }
        #pragma unroll
        for (int q = 0; q < 4; ++q) {         // Lsum cc0 || V staging writes
            Lsum[q] = __builtin_amdgcn_mfma_f32_16x16x32_f16(
                P32a[q], ones8, Lsum[q], 0, 0, 0);
            __builtin_amdgcn_sched_barrier(0);
            if (pre) {
                if (q == 0) *(uint2*)(vdst + vc0) = make_uint2(vr0.x, vr0.y);
                if (q == 1) *(uint2*)(vdst + vc1) = make_uint2(vr0.z, vr0.w);
                if (q == 2) *(uint2*)(vdst + vc2) = make_uint2(vr1.x, vr1.y);
                if (q == 3) *(uint2*)(vdst + vc3) = make_uint2(vr1.z, vr1.w);
            }
            __builtin_amdgcn_sched_barrier(0);
        }
        // PV cc1: O += P(32:63) @ V
        #pragma unroll
        for (int g = 0; g < 4; ++g) {
            #pragma unroll
            for (int q = 0; q < 4; ++q)
                O[q][g] = __builtin_amdgcn_mfma_f32_16x16x32_f16(
                    P32b[q], vfr[g], O[q][g], 0, 0, 0);
            __builtin_amdgcn_sched_barrier(0);
        }
        #pragma unroll
        for (int q = 0; q < 4; ++q)
            Lsum[q] = __builtin_amdgcn_mfma_f32_16x16x32_f16(
                P32b[q], ones8, Lsum[q], 0, 0, 0);
    }

    // finalize: Lsum per-lane (all c16 identical); store
    #pragma unroll
    for (int qg = 0; qg < 4; ++qg) {
        float linv[4];
        #pragma unroll
        for (int r = 0; r < 4; ++r) linv[r] = 1.f / Lsum[qg][r];
        #pragma unroll
        for (int g = 0; g < 4; ++g) {
            const int col = h * HD + g * 16 + c16;
            #pragma unroll
            for (int r = 0; r < 4; ++r) {
                const int s = qt * 256 + w * 64 + qg * 16 + quad * 4 + r;
                AO[((size_t)(b * Sq + s)) * Dm + col] = f2bf(O[qg][g][r] * linv[r]);
            }
        }
    }
}

// ---------------------------------------------------------------------------
extern "C" void kernel_launch(void* const* d_in, const int* in_sizes, int n_in,
                              void* d_out, int out_size, void* d_ws, size_t ws_size,
                              hipStream_t stream)
{
    const float* X  = (const float*)d_in[0];
    const float* Wq = (const float*)d_in[1];
    const float* bq = (const float*)d_in[2];
    const float* Wk = (const float*)d_in[3];
    const float* bk = (const float*)d_in[4];
    const float* Wv = (const float*)d_in[5];
    const float* bv = (const float*)d_in[6];
    const float* Wo = (const float*)d_in[7];
    const float* bo = (const float*)d_in[8];
    float* out = (float*)d_out;

    unsigned short* ws = (unsigned short*)d_ws;
    const size_t NX = (size_t)Bsz * Sq * Dm;   // 8,388,608
    const size_t NW = (size_t)Dm * Dm;         // 1,048,576
    unsigned short* Xb    = ws; ws += NX;
    unsigned short* WtAll = ws; ws += 4 * NW;  // [Wq|Wk|Wv|Wo] transposed bf16
    unsigned short* Qh    = ws; ws += NX;
    unsigned short* Kh    = ws; ws += NX;
    unsigned short* Vt    = ws; ws += NX;
    unsigned short* AO    = ws; ws += NX;

    cvt_bf16<<<(int)(NX / 1024), 256, 0, stream>>>((const float4*)X, (ushort4*)Xb);
    wtrans4<<<dim3(16, 16, 4), 256, 0, stream>>>(Wq, Wk, Wv, Wo, WtAll);

    const float SCL = 0.18033688011112042f;    // 0.125 * log2(e)
    gemm_qkv<<<dim3(3 * Dm / 128, (Bsz * Sq) / 128), 256, 0, stream>>>(
        Xb, WtAll, bq, bk, bv, Qh, Kh, Vt, SCL);

    attn_mfma9<<<dim3(512), 256, 0, stream>>>(Qh, Kh, Vt, AO);

    gemm_o<<<dim3(Dm / 128, (Bsz * Sq) / 128), 256, 0, stream>>>(
        AO, WtAll + 3 * NW, bo, out);
}

// Round 6
// 325.712 us; speedup vs baseline: 1.0359x; 1.0359x over previous
//
#include <hip/hip_runtime.h>

#define Bsz 2
#define Sq  4096
#define Dm  1024
#define NH  16
#define HD  64

typedef __attribute__((ext_vector_type(8))) short short8;   // 8 bf16 = 4 VGPRs
typedef __attribute__((ext_vector_type(4))) float f32x4;
typedef __attribute__((ext_vector_type(2))) __fp16 fp16x2;  // cvt_pkrtz result type
typedef __attribute__((ext_vector_type(4))) _Float16 half4v;
typedef __attribute__((ext_vector_type(8))) _Float16 half8v; // K=32 f16 MFMA operand

__device__ __forceinline__ unsigned short f2bf(float x) {
    unsigned int u = __float_as_uint(x);
    u += 0x7fffu + ((u >> 16) & 1u);            // round-to-nearest-even
    return (unsigned short)(u >> 16);
}

__device__ __forceinline__ void gl2lds16(const unsigned short* g, unsigned short* l) {
    __builtin_amdgcn_global_load_lds(
        (const __attribute__((address_space(1))) unsigned int*)g,
        (__attribute__((address_space(3))) unsigned int*)l, 16, 0, 0);
}

// ---------------------------------------------------------------------------
// fp32 -> bf16 bulk convert (X). 4 elems/thread.
// ---------------------------------------------------------------------------
__global__ __launch_bounds__(256) void cvt_bf16(const float4* __restrict__ in,
                                                ushort4* __restrict__ out) {
    const int i = blockIdx.x * 256 + threadIdx.x;
    const float4 v = in[i];
    ushort4 r;
    r.x = f2bf(v.x); r.y = f2bf(v.y); r.z = f2bf(v.z); r.w = f2bf(v.w);
    out[i] = r;
}

// ---------------------------------------------------------------------------
// Fused weight transpose: W[K][N] fp32 -> WtAll[z][N][K] bf16, z in {q,k,v,o}
// ---------------------------------------------------------------------------
__global__ __launch_bounds__(256) void wtrans4(const float* __restrict__ Wq,
                                               const float* __restrict__ Wk,
                                               const float* __restrict__ Wv,
                                               const float* __restrict__ Wo,
                                               unsigned short* __restrict__ WtAll) {
    __shared__ float tile[64][65];
    const int z = blockIdx.z;
    const float* W = (z == 0) ? Wq : (z == 1) ? Wk : (z == 2) ? Wv : Wo;
    unsigned short* Wt = WtAll + (size_t)z * Dm * Dm;
    const int k0 = blockIdx.y * 64, n0 = blockIdx.x * 64;
    const int t = threadIdx.x;
    #pragma unroll
    for (int i = 0; i < 16; ++i) {
        const int idx = t + i * 256, r = idx >> 6, c = idx & 63;
        tile[r][c] = W[(size_t)(k0 + r) * Dm + n0 + c];
    }
    __syncthreads();
    #pragma unroll
    for (int i = 0; i < 16; ++i) {
        const int idx = t + i * 256, rr = idx >> 6, cc = idx & 63;
        Wt[(size_t)(n0 + rr) * Dm + k0 + cc] = f2bf(tile[cc][rr]);
    }
}

// ---------------------------------------------------------------------------
// V transpose: Vh [bh][s][64] f16 -> Vt [bh][64][Sq] f16. 64x64 LDS tiles,
// coalesced on both sides; tile stored as uint[64][33] (2 hw per uint) so the
// column gather is 2-way-bank (free) and all LDS accesses are 4B-aligned.
// ---------------------------------------------------------------------------
__global__ __launch_bounds__(256) void vtrans(const unsigned short* __restrict__ Vh,
                                              unsigned short* __restrict__ Vt) {
    __shared__ unsigned int tile[64][33];
    const int bh = blockIdx.y;                 // 0..31
    const int st = blockIdx.x;                 // 0..63 (s-tile)
    const int t = threadIdx.x;
    const unsigned short* src = Vh + (size_t)bh * Sq * HD + (size_t)(st * 64) * HD;
    #pragma unroll
    for (int i = 0; i < 4; ++i) {
        const int r = i * 16 + (t >> 4);
        const int c2 = (t & 15) * 2;           // uint col (= 2 hw)
        const uint2 v = *(const uint2*)(src + (size_t)r * HD + c2 * 2);
        tile[r][c2] = v.x;
        tile[r][c2 + 1] = v.y;
    }
    __syncthreads();
    unsigned short* dst = Vt + (size_t)bh * HD * Sq + st * 64;
    #pragma unroll
    for (int i = 0; i < 4; ++i) {
        const int d  = i * 16 + (t >> 4);
        const int s4 = (t & 15) * 4;
        const int c2 = d >> 1, sh = (d & 1) * 16;
        ushort4 v;
        v.x = (unsigned short)(tile[s4 + 0][c2] >> sh);
        v.y = (unsigned short)(tile[s4 + 1][c2] >> sh);
        v.z = (unsigned short)(tile[s4 + 2][c2] >> sh);
        v.w = (unsigned short)(tile[s4 + 3][c2] >> sh);
        *(ushort4*)(dst + (size_t)d * Sq + s4) = v;
    }
}

// ===========================================================================
// Shared GEMM core: 128x128 tile, BK=32, bf16 MFMA, global_load_lds staging.
// ===========================================================================
struct GemmCtx {
    int wm, wn, quad, c16;
    f32x4 acc[4][4];
};

__device__ __forceinline__ void gemm_core(
    const unsigned short* __restrict__ A,
    const unsigned short* __restrict__ Bt,
    int bm, int bn, unsigned short* As, unsigned short* Bs, GemmCtx& cx)
{
    const int t    = threadIdx.x;
    const int w    = t >> 6;
    const int lane = t & 63;
    cx.quad = lane >> 4;
    cx.c16  = lane & 15;
    cx.wm = (w >> 1) * 64;
    cx.wn = (w & 1) * 64;

    #pragma unroll
    for (int i = 0; i < 4; ++i)
        #pragma unroll
        for (int j = 0; j < 4; ++j)
            cx.acc[i][j] = (f32x4){0.f, 0.f, 0.f, 0.f};

    const int srow = lane >> 2, soff = (lane & 3) * 8;
    const unsigned short* Ag0 = A  + (size_t)(bm + w * 16 + srow) * Dm + soff;
    const unsigned short* Ag1 = Ag0 + (size_t)64 * Dm;
    const unsigned short* Bg0 = Bt + (size_t)(bn + w * 16 + srow) * Dm + soff;
    const unsigned short* Bg1 = Bg0 + (size_t)64 * Dm;
    unsigned short* Al0 = As + (w * 16) * 32;
    unsigned short* Al1 = As + (64 + w * 16) * 32;
    unsigned short* Bl0 = Bs + (w * 16) * 32;
    unsigned short* Bl1 = Bs + (64 + w * 16) * 32;

    for (int k0 = 0; k0 < Dm; k0 += 32) {
        __syncthreads();
        gl2lds16(Ag0 + k0, Al0);
        gl2lds16(Ag1 + k0, Al1);
        gl2lds16(Bg0 + k0, Bl0);
        gl2lds16(Bg1 + k0, Bl1);
        __syncthreads();

        short8 af[4], bf[4];
        #pragma unroll
        for (int mt = 0; mt < 4; ++mt)
            af[mt] = *(const short8*)(As + (cx.wm + mt * 16 + cx.c16) * 32 + cx.quad * 8);
        #pragma unroll
        for (int nt = 0; nt < 4; ++nt)
            bf[nt] = *(const short8*)(Bs + (cx.wn + nt * 16 + cx.c16) * 32 + cx.quad * 8);
        #pragma unroll
        for (int mt = 0; mt < 4; ++mt)
            #pragma unroll
            for (int nt = 0; nt < 4; ++nt)
                cx.acc[mt][nt] = __builtin_amdgcn_mfma_f32_16x16x32_bf16(
                    af[mt], bf[nt], cx.acc[mt][nt], 0, 0, 0);
    }
}

// ---------------------------------------------------------------------------
// Fused QKV projection: A=Xb[8192,1024], Bt=WtAll (Wq|Wk|Wv rows, 3072x1024).
// V is written to Vh in the SAME [bh][s][d] layout as K (f16) — the old
// d-major Vt scatter (8KB-stride uint2) amplified 16.8MB of V data into
// ~134MB of line traffic; vtrans produces Vt coalesced afterwards.
// ---------------------------------------------------------------------------
__global__ __launch_bounds__(256) void gemm_qkv(
    const unsigned short* __restrict__ A,
    const unsigned short* __restrict__ WtAll,
    const float* __restrict__ bq, const float* __restrict__ bk,
    const float* __restrict__ bv,
    unsigned short* __restrict__ Qh, unsigned short* __restrict__ Kh,
    unsigned short* __restrict__ Vh, float qscale)
{
    __shared__ unsigned short As[128 * 32];
    __shared__ unsigned short Bs[128 * 32];
    const int bm = blockIdx.y * 128;
    const int bn = blockIdx.x * 128;          // 0..3072
    GemmCtx cx;
    gemm_core(A, WtAll, bm, bn, As, Bs, cx);

    const int which = bn >> 10;               // 0=Q 1=K 2=V
    const float* bias = (which == 0) ? bq : (which == 1) ? bk : bv;
    const float osc = (which == 0) ? qscale : 1.0f;

    #pragma unroll
    for (int mt = 0; mt < 4; ++mt) {
        const int m0 = bm + cx.wm + mt * 16 + cx.quad * 4;
        #pragma unroll
        for (int nt = 0; nt < 4; ++nt) {
            const int n  = bn + cx.wn + nt * 16 + cx.c16;
            const int nl = n & 1023;
            const float bvv = bias[nl];
            const int h = (nl >> 6), d = nl & 63;
            if (which < 2) {
                unsigned short* C = (which == 0) ? Qh : Kh;
                #pragma unroll
                for (int r = 0; r < 4; ++r) {
                    const int m = m0 + r;
                    const int b = m >> 12, s = m & (Sq - 1);
                    C[((size_t)(b * NH + h) * Sq + s) * HD + d] =
                        f2bf((cx.acc[mt][nt][r] + bvv) * osc);
                }
            } else {
                union { fp16x2 h2; unsigned int u; } p01, p23;
                p01.h2 = __builtin_amdgcn_cvt_pkrtz(cx.acc[mt][nt][0] + bvv,
                                                    cx.acc[mt][nt][1] + bvv);
                p23.h2 = __builtin_amdgcn_cvt_pkrtz(cx.acc[mt][nt][2] + bvv,
                                                    cx.acc[mt][nt][3] + bvv);
                const unsigned short hw[4] = {
                    (unsigned short)p01.u, (unsigned short)(p01.u >> 16),
                    (unsigned short)p23.u, (unsigned short)(p23.u >> 16) };
                #pragma unroll
                for (int r = 0; r < 4; ++r) {
                    const int m = m0 + r;
                    const int b = m >> 12, s = m & (Sq - 1);
                    Vh[((size_t)(b * NH + h) * Sq + s) * HD + d] = hw[r];
                }
            }
        }
    }
}

// ---------------------------------------------------------------------------
// Output projection: fp32 out = AO @ Wo^T + bo
// ---------------------------------------------------------------------------
__global__ __launch_bounds__(256) void gemm_o(
    const unsigned short* __restrict__ A,
    const unsigned short* __restrict__ Bt,
    const float* __restrict__ bias, float* __restrict__ C)
{
    __shared__ unsigned short As[128 * 32];
    __shared__ unsigned short Bs[128 * 32];
    const int bm = blockIdx.y * 128;
    const int bn = blockIdx.x * 128;
    GemmCtx cx;
    gemm_core(A, Bt, bm, bn, As, Bs, cx);

    #pragma unroll
    for (int mt = 0; mt < 4; ++mt) {
        const int m0 = bm + cx.wm + mt * 16 + cx.quad * 4;
        #pragma unroll
        for (int nt = 0; nt < 4; ++nt) {
            const int n = bn + cx.wn + nt * 16 + cx.c16;
            const float bvv = bias[n];
            #pragma unroll
            for (int r = 0; r < 4; ++r)
                C[(size_t)(m0 + r) * Dm + n] = cx.acc[mt][nt][r] + bvv;
        }
    }
}

// ---------------------------------------------------------------------------
// Flash attention v8 (best measured): qg=4, XOR-swizzled LDS, XCD-grouped
// grid (FETCH 139->25MB), cluster-rotated schedule, setprio around MFMA.
// Q,K: bf16 [B*NH][Sq][64] (Q pre-scaled by 0.125*log2e). Vt: fp16 [B*NH][64][Sq].
// ---------------------------------------------------------------------------
__global__ __launch_bounds__(256, 2) void attn_mfma8(
    const unsigned short* __restrict__ Q,
    const unsigned short* __restrict__ K,
    const unsigned short* __restrict__ Vt,
    unsigned short* __restrict__ AO)
{
    __shared__ unsigned short Ks[2][64 * 64];   // [key][d] bf16, XOR-swizzled rows
    __shared__ unsigned short Vs[2][64 * 64];   // [d][pos] fp16, key-permuted + swz

    // XCD-grouped decode: xcd = wg&7, 64 blocks per XCD cover 4 bh x 16 qt.
    const int wg  = blockIdx.x;               // 0..511
    const int j   = wg >> 3;                  // 0..63 within XCD
    const int bh  = (wg & 7) * 4 + (j >> 4);  // 0..31
    const int qt  = j & 15;                   // 0..15 (256 queries each)
    const int b = bh >> 4, h = bh & 15;
    const int t    = threadIdx.x;
    const int w    = t >> 6;
    const int lane = t & 63;
    const int quad = lane >> 4;
    const int c16  = lane & 15;
    const size_t base = (size_t)bh * Sq * HD;

    // Q B-frags: 4 query-groups x 2 k-halves, held all kernel
    short8 qf[4][2];
    #pragma unroll
    for (int qg = 0; qg < 4; ++qg) {
        const unsigned short* qp =
            Q + base + (size_t)(qt * 256 + w * 64 + qg * 16 + c16) * HD;
        qf[qg][0] = *(const short8*)(qp + quad * 8);
        qf[qg][1] = *(const short8*)(qp + 32 + quad * 8);
    }

    f32x4 O[4][4];                 // [qg][d-group]
    f32x4 Lsum[4];
    #pragma unroll
    for (int qg = 0; qg < 4; ++qg) {
        Lsum[qg] = (f32x4){0.f, 0.f, 0.f, 0.f};
        #pragma unroll
        for (int g = 0; g < 4; ++g)
            O[qg][g] = (f32x4){0.f, 0.f, 0.f, 0.f};
    }
    half8v ones8;
    #pragma unroll
    for (int i = 0; i < 8; ++i) ones8[i] = (_Float16)1.f;

    // staging geometry: row = t>>2 (0..63), chunk = (t&3)*8 halfwords
    const int srow = t >> 2, sc4 = (t & 3) * 8;
    const int swr = (srow & 7) << 3;          // staging-row XOR swizzle (halfwords)
    // V key-permutation for 4-key subchunks starting at m (within 32-group)
    const int f0 = (sc4 < 16) ? sc4 * 2 : (sc4 - 16) * 2 + 4;        // {0,16,4,20}
    const int f1 = (sc4 + 4 < 16) ? (sc4 + 4) * 2 : (sc4 - 12) * 2 + 4; // {8,24,12,28}
    // swizzled staging columns
    const int kc0 = sc4 ^ swr, kc1 = (sc4 + 32) ^ swr;
    const int vc0 = f0 ^ swr, vc1 = f1 ^ swr;
    const int vc2 = (32 + f0) ^ swr, vc3 = (32 + f1) ^ swr;

    const unsigned short* kg = K  + base + (size_t)srow * HD + sc4;
    const unsigned short* vg = Vt + base + (size_t)srow * Sq + sc4;
    unsigned short* ksl = &Ks[0][0] + srow * 64;
    unsigned short* vsl = &Vs[0][0] + srow * 64;
    const int LBUF = 64 * 64;

    int4 kr0, kr1, vr0, vr1;
    kr0 = *(const int4*)(kg);
    kr1 = *(const int4*)(kg + 32);
    vr0 = *(const int4*)(vg);
    vr1 = *(const int4*)(vg + 32);
    *(int4*)(ksl + kc0) = kr0;
    *(int4*)(ksl + kc1) = kr1;
    *(uint2*)(vsl + vc0) = make_uint2(vr0.x, vr0.y);
    *(uint2*)(vsl + vc1) = make_uint2(vr0.z, vr0.w);
    *(uint2*)(vsl + vc2) = make_uint2(vr1.x, vr1.y);
    *(uint2*)(vsl + vc3) = make_uint2(vr1.z, vr1.w);

    for (int kt = 0; kt < Sq / 64; ++kt) {
        const int cur = kt & 1;
        if (kt + 1 < Sq / 64) {               // prefetch next tile into regs
            const unsigned short* kp = kg + (size_t)(kt + 1) * 64 * HD;
            const unsigned short* vp = vg + (kt + 1) * 64;
            kr0 = *(const int4*)(kp);
            kr1 = *(const int4*)(kp + 32);
            vr0 = *(const int4*)(vp);
            vr1 = *(const int4*)(vp + 32);
        }
        __syncthreads();

        const unsigned short* ksb = &Ks[cur][0];
        const unsigned short* vsb = &Vs[cur][0];

        f32x4 z0[4], z1[4], z2[4], z3[4];
        half4v P4[4][4];          // [nt][qg]

        // --- pipeline stages ---------------------------------------------
        auto qkstep = [&](int nt5, f32x4* z) {
            const int krow = nt5 * 16 + c16;
            const int ksw = (krow & 7) << 3;
            const short8 kf0 = *(const short8*)(ksb + krow * 64 + ((quad * 8) ^ ksw));
            const short8 kf1 = *(const short8*)(ksb + krow * 64 + ((32 + quad * 8) ^ ksw));
            __builtin_amdgcn_s_setprio(1);
            #pragma unroll
            for (int qg = 0; qg < 4; ++qg) {
                f32x4 zz = (f32x4){0.f, 0.f, 0.f, 0.f};
                zz = __builtin_amdgcn_mfma_f32_16x16x32_bf16(kf0, qf[qg][0], zz, 0, 0, 0);
                zz = __builtin_amdgcn_mfma_f32_16x16x32_bf16(kf1, qf[qg][1], zz, 0, 0, 0);
                z[qg] = zz;
            }
            __builtin_amdgcn_s_setprio(0);
            __builtin_amdgcn_sched_barrier(0);
        };
        auto expstep = [&](const f32x4* z, half4v* Pn) {
            #pragma unroll
            for (int qg = 0; qg < 4; ++qg) {
                const float p0 = __builtin_amdgcn_exp2f(z[qg][0]);
                const float p1 = __builtin_amdgcn_exp2f(z[qg][1]);
                const float p2 = __builtin_amdgcn_exp2f(z[qg][2]);
                const float p3 = __builtin_amdgcn_exp2f(z[qg][3]);
                union { fp16x2 h2[2]; half4v h4; } pk;
                pk.h2[0] = __builtin_amdgcn_cvt_pkrtz(p0, p1);
                pk.h2[1] = __builtin_amdgcn_cvt_pkrtz(p2, p3);
                Pn[qg] = pk.h4;
            }
        };
        auto pvstep = [&](int cc) {
            half8v P32[4];
            #pragma unroll
            for (int qg = 0; qg < 4; ++qg) {
                union { half4v h4[2]; half8v h8; } u;
                u.h4[0] = P4[2 * cc][qg];
                u.h4[1] = P4[2 * cc + 1][qg];
                P32[qg] = u.h8;
            }
            half8v vf[4];
            #pragma unroll
            for (int g = 0; g < 4; ++g) {
                const int vrow = g * 16 + c16;
                vf[g] = *(const half8v*)
                    (vsb + vrow * 64 + ((cc * 32 + quad * 8) ^ ((vrow & 7) << 3)));
            }
            __builtin_amdgcn_s_setprio(1);
            #pragma unroll
            for (int g = 0; g < 4; ++g)
                #pragma unroll
                for (int qg = 0; qg < 4; ++qg)
                    O[qg][g] = __builtin_amdgcn_mfma_f32_16x16x32_f16(
                        P32[qg], vf[g], O[qg][g], 0, 0, 0);
            #pragma unroll
            for (int qg = 0; qg < 4; ++qg)
                Lsum[qg] = __builtin_amdgcn_mfma_f32_16x16x32_f16(
                    P32[qg], ones8, Lsum[qg], 0, 0, 0);
            __builtin_amdgcn_s_setprio(0);
            __builtin_amdgcn_sched_barrier(0);
        };

        // --- rotated schedule: MFMA(n) || VALU(n-1) ----------------------
        qkstep(0, z0);
        qkstep(1, z1);  expstep(z0, P4[0]);
        qkstep(2, z2);  expstep(z1, P4[1]);
        qkstep(3, z3);  expstep(z2, P4[2]);
        pvstep(0);
        expstep(z3, P4[3]);
        if (kt + 1 < Sq / 64) {               // K staging under PV(cc0) shadow
            const int nb = cur ^ 1;
            *(int4*)(ksl + nb * LBUF + kc0) = kr0;
            *(int4*)(ksl + nb * LBUF + kc1) = kr1;
        }
        pvstep(1);
        if (kt + 1 < Sq / 64) {               // V staging under PV(cc1) shadow
            const int nb = cur ^ 1;
            unsigned short* vdst = vsl + nb * LBUF;
            *(uint2*)(vdst + vc0) = make_uint2(vr0.x, vr0.y);
            *(uint2*)(vdst + vc1) = make_uint2(vr0.z, vr0.w);
            *(uint2*)(vdst + vc2) = make_uint2(vr1.x, vr1.y);
            *(uint2*)(vdst + vc3) = make_uint2(vr1.z, vr1.w);
        }
    }

    // finalize: Lsum per-lane (all c16 identical); store
    #pragma unroll
    for (int qg = 0; qg < 4; ++qg) {
        float linv[4];
        #pragma unroll
        for (int r = 0; r < 4; ++r) linv[r] = 1.f / Lsum[qg][r];
        #pragma unroll
        for (int g = 0; g < 4; ++g) {
            const int col = h * HD + g * 16 + c16;
            #pragma unroll
            for (int r = 0; r < 4; ++r) {
                const int s = qt * 256 + w * 64 + qg * 16 + quad * 4 + r;
                AO[((size_t)(b * Sq + s)) * Dm + col] = f2bf(O[qg][g][r] * linv[r]);
            }
        }
    }
}

// ---------------------------------------------------------------------------
extern "C" void kernel_launch(void* const* d_in, const int* in_sizes, int n_in,
                              void* d_out, int out_size, void* d_ws, size_t ws_size,
                              hipStream_t stream)
{
    const float* X  = (const float*)d_in[0];
    const float* Wq = (const float*)d_in[1];
    const float* bq = (const float*)d_in[2];
    const float* Wk = (const float*)d_in[3];
    const float* bk = (const float*)d_in[4];
    const float* Wv = (const float*)d_in[5];
    const float* bv = (const float*)d_in[6];
    const float* Wo = (const float*)d_in[7];
    const float* bo = (const float*)d_in[8];
    float* out = (float*)d_out;

    unsigned short* ws = (unsigned short*)d_ws;
    const size_t NX = (size_t)Bsz * Sq * Dm;   // 8,388,608
    const size_t NW = (size_t)Dm * Dm;         // 1,048,576
    unsigned short* Xb    = ws; ws += NX;
    unsigned short* WtAll = ws; ws += 4 * NW;  // [Wq|Wk|Wv|Wo] transposed bf16
    unsigned short* Qh    = ws; ws += NX;
    unsigned short* Kh    = ws; ws += NX;
    unsigned short* Vt    = ws; ws += NX;
    unsigned short* AO    = ws; ws += NX;
    unsigned short* Vh    = AO;                // alias: Vh dead before AO written

    cvt_bf16<<<(int)(NX / 1024), 256, 0, stream>>>((const float4*)X, (ushort4*)Xb);
    wtrans4<<<dim3(16, 16, 4), 256, 0, stream>>>(Wq, Wk, Wv, Wo, WtAll);

    const float SCL = 0.18033688011112042f;    // 0.125 * log2(e)
    gemm_qkv<<<dim3(3 * Dm / 128, (Bsz * Sq) / 128), 256, 0, stream>>>(
        Xb, WtAll, bq, bk, bv, Qh, Kh, Vh, SCL);

    vtrans<<<dim3(Sq / 64, Bsz * NH), 256, 0, stream>>>(Vh, Vt);

    attn_mfma8<<<dim3(512), 256, 0, stream>>>(Qh, Kh, Vt, AO);

    gemm_o<<<dim3(Dm / 128, (Bsz * Sq) / 128), 256, 0, stream>>>(
        AO, WtAll + 3 * NW, bo, out);
}